// Round 3
// baseline (3547.897 us; speedup 1.0000x reference)
//
#include <hip/hip_runtime.h>

// ---------------------------------------------------------------------------
// BiSSM global block, MI355X — round 3: phase-decomposed scan (J=16).
//   V16[t] = sum_{j<16} u[t-j] @ (A^j)^T  via 4 doubling GEMMs (fwd+bwd fused)
//   h_t = h_{t-16} @ (A^16)^T + V16[t]  -> 256 independent seqs of length 128
//   3-level chunked scan: L1 (M1=A^16, S=4, 32 chunks, 256 blocks, M=32 rows)
//                         L2 (M2=A^64, S=4, 8 chunks, 64 blocks)
//                         L3 (M3=A^256, S=8, 1 chunk, 8 blocks)
//   then L2b, L1b reruns with inits; k_final fuses y/gate/skip.
// Precision: scan matrices bf16 + f32 diag residual; power chain hi/lo bf16.
// ---------------------------------------------------------------------------

typedef short  bfrag __attribute__((ext_vector_type(8)));   // 8 x bf16
typedef float  ffrag __attribute__((ext_vector_type(4)));   // mfma acc
typedef float  f4    __attribute__((ext_vector_type(4)));

#define DEV static __device__ __forceinline__

DEV unsigned short f2bf(float f) {
  unsigned u = __float_as_uint(f);
  u += 0x7fffu + ((u >> 16) & 1u);            // round-to-nearest-even
  return (unsigned short)(u >> 16);
}
DEV float bf2f(unsigned short s) { return __uint_as_float(((unsigned)s) << 16); }

DEV ffrag mfma16(bfrag a, bfrag b, ffrag c) {
  return __builtin_amdgcn_mfma_f32_16x16x32_bf16(a, b, c, 0, 0, 0);
}

union BF8 { bfrag v; unsigned short u[8]; };

#define Hn 768
#define Nn 2048
#define Bb 8

// ---------------------------------------------------------------------------
// k_abuild: gridDim = (768, 4); task = blockIdx.y
__global__ __launch_bounds__(256) void k_abuild(
    const float* __restrict__ U, const float* __restrict__ V,
    const float* __restrict__ S, const float* __restrict__ Bm,
    const float* __restrict__ Cm, const float* __restrict__ gw,
    float* __restrict__ Af, float* __restrict__ AfT,
    unsigned short* __restrict__ Abf, float* __restrict__ dresA,
    unsigned short* __restrict__ Bmb, unsigned short* __restrict__ Cmb,
    unsigned short* __restrict__ gwb) {
  int i = blockIdx.x;
  int task = blockIdx.y;
  if (task == 0) {
    float u0 = U[i*4+0], u1 = U[i*4+1], u2 = U[i*4+2], u3 = U[i*4+3];
    for (int j = threadIdx.x; j < Hn; j += 256) {
      float a = u0*V[j*4+0] + u1*V[j*4+1] + u2*V[j*4+2] + u3*V[j*4+3]
              + S[i*Hn+j] - S[j*Hn+i];
      if (i == j) a += -(float)(i+1) / 768.0f;
      Af[i*Hn+j]  = a;
      AfT[j*Hn+i] = a;
      unsigned short ab = f2bf(a);
      Abf[i*Hn+j] = ab;
      if (i == j) dresA[i] = a - bf2f(ab);
    }
  } else {
    const float* src = (task==1) ? Bm : (task==2) ? Cm : gw;
    unsigned short* dst = (task==1) ? Bmb : (task==2) ? Cmb : gwb;
    for (int j = threadIdx.x; j < Hn; j += 256) dst[i*Hn+j] = f2bf(src[i*Hn+j]);
  }
}

// ---------------------------------------------------------------------------
// k_rms: one wave per row (row = b*2048 + t); write xn in (t,b) order, bf16.
__global__ __launch_bounds__(256) void k_rms(
    const float* __restrict__ x, const float* __restrict__ scale,
    unsigned short* __restrict__ xn) {
  int row  = blockIdx.x * 4 + (threadIdx.x >> 6);
  int lane = threadIdx.x & 63;
  int b = row >> 11, t = row & 2047;
  const float* xr = x + (long)row * Hn;
  float v[12];
  float ss = 0.f;
#pragma unroll
  for (int j = 0; j < 12; ++j) { v[j] = xr[lane + j*64]; ss += v[j]*v[j]; }
#pragma unroll
  for (int off = 1; off < 64; off <<= 1) ss += __shfl_xor(ss, off);
  float inv = 1.0f / sqrtf(ss / 768.0f + 1e-8f);
  unsigned short* dst = xn + ((long)t * Bb + b) * Hn;
#pragma unroll
  for (int j = 0; j < 12; ++j) dst[lane + j*64] = f2bf(v[j] * inv * scale[lane + j*64]);
}

// ---------------------------------------------------------------------------
// k_gemm_u: u = xn @ Bm^T.  grid (256, 6), 512 thr. tile 64 rows x 128 cols.
__global__ __launch_bounds__(512) void k_gemm_u(
    const unsigned short* __restrict__ xn, const unsigned short* __restrict__ Bmb,
    unsigned short* __restrict__ u) {
  int tid = threadIdx.x, lane = tid & 63, w = tid >> 6;
  int mw = w >> 2, nw = w & 3, l15 = lane & 15, lhi = lane >> 4;
  long rb = (long)blockIdx.x * 64;
  int  cb = blockIdx.y * 128;
  ffrag acc[2][2] = {};
  for (int kt = 0; kt < 24; ++kt) {
    int k0 = kt*32 + lhi*8;
    bfrag a[2], b[2];
#pragma unroll
    for (int mt = 0; mt < 2; ++mt)
      a[mt] = *(const bfrag*)(xn + (rb + mw*32 + mt*16 + l15) * Hn + k0);
#pragma unroll
    for (int nt = 0; nt < 2; ++nt)
      b[nt] = *(const bfrag*)(Bmb + (long)(cb + nw*32 + nt*16 + l15) * Hn + k0);
#pragma unroll
    for (int mt = 0; mt < 2; ++mt)
#pragma unroll
      for (int nt = 0; nt < 2; ++nt)
        acc[mt][nt] = mfma16(a[mt], b[nt], acc[mt][nt]);
  }
#pragma unroll
  for (int mt = 0; mt < 2; ++mt)
#pragma unroll
    for (int nt = 0; nt < 2; ++nt)
#pragma unroll
      for (int q = 0; q < 4; ++q) {
        long grow = rb + mw*32 + mt*16 + lhi*4 + q;
        int  gcol = cb + nw*32 + nt*16 + l15;
        u[grow * Hn + gcol] = f2bf(acc[mt][nt][q]);
      }
}

// ---------------------------------------------------------------------------
// k_sq: Z = X @ X, hi/lo bf16 (3 passes). Writes Z rm + Z^T rm f32; optional
// bf16 + diag residual. grid (12, 6), 512 thr, tile 64x128.
__global__ __launch_bounds__(512) void k_sq(
    const float* __restrict__ X, const float* __restrict__ XT,
    float* __restrict__ Z, float* __restrict__ ZT,
    unsigned short* __restrict__ Zbf, float* __restrict__ dresZ) {
  int tid = threadIdx.x, lane = tid & 63, w = tid >> 6;
  int mw = w >> 2, nw = w & 3, l15 = lane & 15, lhi = lane >> 4;
  int rb = blockIdx.x * 64, cb = blockIdx.y * 128;
  ffrag acc[2][2] = {};
  for (int kt = 0; kt < 24; ++kt) {
    int k0 = kt*32 + lhi*8;
    BF8 ah[2], al[2], bh[2], bl[2];
#pragma unroll
    for (int mt = 0; mt < 2; ++mt) {
      const f4* p = (const f4*)(X + (long)(rb + mw*32 + mt*16 + l15) * Hn + k0);
      f4 x0 = p[0], x1 = p[1];
#pragma unroll
      for (int j = 0; j < 8; ++j) {
        float f = (j < 4) ? x0[j] : x1[j-4];
        unsigned short h = f2bf(f);
        ah[mt].u[j] = h; al[mt].u[j] = f2bf(f - bf2f(h));
      }
    }
#pragma unroll
    for (int nt = 0; nt < 2; ++nt) {
      const f4* p = (const f4*)(XT + (long)(cb + nw*32 + nt*16 + l15) * Hn + k0);
      f4 x0 = p[0], x1 = p[1];
#pragma unroll
      for (int j = 0; j < 8; ++j) {
        float f = (j < 4) ? x0[j] : x1[j-4];
        unsigned short h = f2bf(f);
        bh[nt].u[j] = h; bl[nt].u[j] = f2bf(f - bf2f(h));
      }
    }
#pragma unroll
    for (int mt = 0; mt < 2; ++mt)
#pragma unroll
      for (int nt = 0; nt < 2; ++nt) {
        acc[mt][nt] = mfma16(ah[mt].v, bh[nt].v, acc[mt][nt]);
        acc[mt][nt] = mfma16(ah[mt].v, bl[nt].v, acc[mt][nt]);
        acc[mt][nt] = mfma16(al[mt].v, bh[nt].v, acc[mt][nt]);
      }
  }
#pragma unroll
  for (int mt = 0; mt < 2; ++mt)
#pragma unroll
    for (int nt = 0; nt < 2; ++nt)
#pragma unroll
      for (int q = 0; q < 4; ++q) {
        int grow = rb + mw*32 + mt*16 + lhi*4 + q;
        int gcol = cb + nw*32 + nt*16 + l15;
        float vv = acc[mt][nt][q];
        Z[(long)grow*Hn + gcol] = vv;
        ZT[(long)gcol*Hn + grow] = vv;
        if (Zbf) Zbf[(long)grow*Hn + gcol] = f2bf(vv);
        if (dresZ && grow == gcol) dresZ[gcol] = vv - bf2f(f2bf(vv));
      }
}

// ---------------------------------------------------------------------------
// k_dbl: V_{2k}[t] = V_k[t] + V_k[t -/+ k] @ W   (W = A^k bf16, row-major)
// fwd rows (blockIdx.x < 256) shift -k; bwd shift +k; OOB rows contribute 0.
// grid (512, 6), 512 thr, tile 64 rows x 128 cols. Rows are (t*8+b).
__global__ __launch_bounds__(512) void k_dbl(
    const unsigned short* __restrict__ inF, const unsigned short* __restrict__ inB,
    unsigned short* __restrict__ outF, unsigned short* __restrict__ outB,
    const unsigned short* __restrict__ Wb, int shift8) {
  int tid = threadIdx.x, lane = tid & 63, w = tid >> 6;
  int mw = w >> 2, nw = w & 3, l15 = lane & 15, lhi = lane >> 4;
  int bx = blockIdx.x;
  int dir = bx >> 8;                       // 0 fwd, 1 bwd
  long rb64 = (long)(bx & 255) * 64;
  int cb = blockIdx.y * 128;
  const unsigned short* in = dir ? inB : inF;
  unsigned short* out = dir ? outB : outF;
  int sh = dir ? shift8 : -shift8;
  ffrag acc[2][2] = {};
  for (int kt = 0; kt < 24; ++kt) {
    int k0 = kt*32 + lhi*8;
    bfrag a[2] = {}, b[2];
#pragma unroll
    for (int mt = 0; mt < 2; ++mt) {
      long r = rb64 + mw*32 + mt*16 + l15 + sh;
      if (r >= 0 && r < 16384)
        a[mt] = *(const bfrag*)(in + r * Hn + k0);
    }
#pragma unroll
    for (int nt = 0; nt < 2; ++nt)
      b[nt] = *(const bfrag*)(Wb + (long)(cb + nw*32 + nt*16 + l15) * Hn + k0);
#pragma unroll
    for (int mt = 0; mt < 2; ++mt)
#pragma unroll
      for (int nt = 0; nt < 2; ++nt)
        acc[mt][nt] = mfma16(a[mt], b[nt], acc[mt][nt]);
  }
#pragma unroll
  for (int mt = 0; mt < 2; ++mt)
#pragma unroll
    for (int nt = 0; nt < 2; ++nt)
#pragma unroll
      for (int q = 0; q < 4; ++q) {
        long row = rb64 + mw*32 + mt*16 + lhi*4 + q;
        int  col = cb + nw*32 + nt*16 + l15;
        out[row*Hn + col] = f2bf(acc[mt][nt][q] + bf2f(in[row*Hn + col]));
      }
}

// ---------------------------------------------------------------------------
// k_scanL1: level-1 chunked scan over V16 (bf16), M=32 rows, 8 waves.
// grid 256: c = bx&31 (chunk, S=4 steps), rb = bx>>5 (row-block 0..7).
// rb<4 fwd (phases rb*4..rb*4+3), rb>=4 bwd. Rows r = pl*8+b (pl=phase lane).
__global__ __launch_bounds__(512, 4) void k_scanL1(
    const unsigned short* __restrict__ mat, const float* __restrict__ dres,
    const unsigned short* __restrict__ Vf, const unsigned short* __restrict__ Vb,
    const float* __restrict__ init,          // scanE1 (use c-1) or null
    unsigned short* __restrict__ hf, unsigned short* __restrict__ hb, // pass2
    float* __restrict__ edge) {              // pass1 out [32][256][768]
  __shared__ unsigned short hbuf[32][776];
  const int tid = threadIdx.x, lane = tid & 63, w = tid >> 6;
  const int l15 = lane & 15, lhi = lane >> 4;
  const int bx = blockIdx.x;
  const int c = bx & 31, rb = bx >> 5;
  const int dir = rb >> 2, rb2 = rb & 3;
  const unsigned short* V = dir ? Vb : Vf;
  unsigned short* hout = dir ? hb : hf;

  for (int r = 0; r < 32; ++r)
    for (int col = tid; col < Hn; col += 512) {
      float v = 0.f;
      if (init && c > 0) v = init[((long)(c-1)*256 + rb*32 + r)*Hn + col];
      hbuf[r][col] = f2bf(v);
    }
  __syncthreads();

  ffrag acc[2][6];
  for (int s = 0; s < 4; ++s) {
    const int st = 4*c + s;
    const int basef = rb2*32 + 128*st;
    const int baseb = 16376 - rb2*32 - 128*st;
    // acc <- V
#pragma unroll
    for (int mt = 0; mt < 2; ++mt)
#pragma unroll
      for (int j = 0; j < 6; ++j) {
        int n = w*96 + j*16 + l15;
#pragma unroll
        for (int q = 0; q < 4; ++q) {
          int m = mt*16 + lhi*4 + q;
          int vr = dir ? (baseb - 8*(m>>3) + (m&7)) : (basef + m);
          acc[mt][j][q] = bf2f(V[(long)vr*Hn + n]);
        }
      }
    // acc += h @ Mat
    for (int kt = 0; kt < 24; ++kt) {
      int k0 = kt*32 + lhi*8;
      bfrag a0 = *(const bfrag*)&hbuf[l15][k0];
      bfrag a1 = *(const bfrag*)&hbuf[16 + l15][k0];
#pragma unroll
      for (int j = 0; j < 6; ++j) {
        int n = w*96 + j*16 + l15;
        bfrag bb = *(const bfrag*)(mat + (long)n*Hn + k0);
        acc[0][j] = mfma16(a0, bb, acc[0][j]);
        acc[1][j] = mfma16(a1, bb, acc[1][j]);
      }
    }
    // diag residual (old h)
#pragma unroll
    for (int j = 0; j < 6; ++j) {
      int n = w*96 + j*16 + l15;
      float dv = dres[n];
#pragma unroll
      for (int mt = 0; mt < 2; ++mt)
#pragma unroll
        for (int q = 0; q < 4; ++q) {
          int m = mt*16 + lhi*4 + q;
          acc[mt][j][q] += bf2f(hbuf[m][n]) * dv;
        }
    }
    __syncthreads();
    // h <- acc (+ optional bf16 out)
#pragma unroll
    for (int mt = 0; mt < 2; ++mt)
#pragma unroll
      for (int j = 0; j < 6; ++j) {
        int n = w*96 + j*16 + l15;
#pragma unroll
        for (int q = 0; q < 4; ++q) {
          int m = mt*16 + lhi*4 + q;
          unsigned short hv = f2bf(acc[mt][j][q]);
          hbuf[m][n] = hv;
          if (hout) {
            int vr = dir ? (baseb - 8*(m>>3) + (m&7)) : (basef + m);
            hout[(long)vr*Hn + n] = hv;
          }
        }
      }
    __syncthreads();
  }
  if (edge) {
#pragma unroll
    for (int mt = 0; mt < 2; ++mt)
#pragma unroll
      for (int j = 0; j < 6; ++j) {
        int n = w*96 + j*16 + l15;
#pragma unroll
        for (int q = 0; q < 4; ++q) {
          int m = mt*16 + lhi*4 + q;
          edge[((long)c*256 + rb*32 + m)*Hn + n] = acc[mt][j][q];
        }
      }
  }
}

// ---------------------------------------------------------------------------
// k_scanE: edge-level scan. buf layout [steps][256][768] f32.
// grid = nchunks*8: rb = bx&7 (32 rows), c = bx>>3. S steps per chunk.
__global__ __launch_bounds__(512, 4) void k_scanE(
    const unsigned short* __restrict__ mat, const float* __restrict__ dres,
    float* __restrict__ buf, const float* __restrict__ init,
    float* __restrict__ edge, int S, int inplace) {
  __shared__ unsigned short hbuf[32][776];
  const int tid = threadIdx.x, lane = tid & 63, w = tid >> 6;
  const int l15 = lane & 15, lhi = lane >> 4;
  const int bx = blockIdx.x;
  const int rb = bx & 7, c = bx >> 3;

  for (int r = 0; r < 32; ++r)
    for (int col = tid; col < Hn; col += 512) {
      float v = 0.f;
      if (init && c > 0) v = init[((long)(c-1)*256 + rb*32 + r)*Hn + col];
      hbuf[r][col] = f2bf(v);
    }
  __syncthreads();

  ffrag acc[2][6];
  for (int s = 0; s < S; ++s) {
    const long rowbase = ((long)(c*S + s)*256 + rb*32);
#pragma unroll
    for (int mt = 0; mt < 2; ++mt)
#pragma unroll
      for (int j = 0; j < 6; ++j) {
        int n = w*96 + j*16 + l15;
#pragma unroll
        for (int q = 0; q < 4; ++q) {
          int m = mt*16 + lhi*4 + q;
          acc[mt][j][q] = buf[(rowbase + m)*Hn + n];
        }
      }
    for (int kt = 0; kt < 24; ++kt) {
      int k0 = kt*32 + lhi*8;
      bfrag a0 = *(const bfrag*)&hbuf[l15][k0];
      bfrag a1 = *(const bfrag*)&hbuf[16 + l15][k0];
#pragma unroll
      for (int j = 0; j < 6; ++j) {
        int n = w*96 + j*16 + l15;
        bfrag bb = *(const bfrag*)(mat + (long)n*Hn + k0);
        acc[0][j] = mfma16(a0, bb, acc[0][j]);
        acc[1][j] = mfma16(a1, bb, acc[1][j]);
      }
    }
#pragma unroll
    for (int j = 0; j < 6; ++j) {
      int n = w*96 + j*16 + l15;
      float dv = dres[n];
#pragma unroll
      for (int mt = 0; mt < 2; ++mt)
#pragma unroll
        for (int q = 0; q < 4; ++q) {
          int m = mt*16 + lhi*4 + q;
          acc[mt][j][q] += bf2f(hbuf[m][n]) * dv;
        }
    }
    __syncthreads();
#pragma unroll
    for (int mt = 0; mt < 2; ++mt)
#pragma unroll
      for (int j = 0; j < 6; ++j) {
        int n = w*96 + j*16 + l15;
#pragma unroll
        for (int q = 0; q < 4; ++q) {
          int m = mt*16 + lhi*4 + q;
          float v = acc[mt][j][q];
          hbuf[m][n] = f2bf(v);
          if (inplace) buf[(rowbase + m)*Hn + n] = v;
        }
      }
    __syncthreads();
  }
  if (edge) {
#pragma unroll
    for (int mt = 0; mt < 2; ++mt)
#pragma unroll
      for (int j = 0; j < 6; ++j) {
        int n = w*96 + j*16 + l15;
#pragma unroll
        for (int q = 0; q < 4; ++q) {
          int m = mt*16 + lhi*4 + q;
          edge[((long)c*256 + rb*32 + m)*Hn + n] = acc[mt][j][q];
        }
      }
  }
}

// ---------------------------------------------------------------------------
// k_final: out = x + alpha * 0.5*((hf+hb)@Cm^T) * sigmoid(xn@gw^T + gb)
__global__ __launch_bounds__(512) void k_final(
    const unsigned short* __restrict__ xn, const unsigned short* __restrict__ hf,
    const unsigned short* __restrict__ hb,
    const unsigned short* __restrict__ Cmb, const unsigned short* __restrict__ gwb,
    const float* __restrict__ gate_b, const float* __restrict__ alpha,
    const float* __restrict__ x, float* __restrict__ out) {
  int tid = threadIdx.x, lane = tid & 63, w = tid >> 6;
  int mw = w >> 2, nw = w & 3, l15 = lane & 15, lhi = lane >> 4;
  long rb = (long)blockIdx.x * 64;
  int  cb = blockIdx.y * 128;
  ffrag ay[2][2] = {}, az[2][2] = {};
  for (int kt = 0; kt < 24; ++kt) {
    int k0 = kt*32 + lhi*8;
    bfrag axv[2], afv[2], abv[2], bcv[2], bgv[2];
#pragma unroll
    for (int mt = 0; mt < 2; ++mt) {
      long r = (rb + mw*32 + mt*16 + l15) * Hn + k0;
      axv[mt] = *(const bfrag*)(xn + r);
      afv[mt] = *(const bfrag*)(hf + r);
      abv[mt] = *(const bfrag*)(hb + r);
    }
#pragma unroll
    for (int nt = 0; nt < 2; ++nt) {
      long cc = (long)(cb + nw*32 + nt*16 + l15) * Hn + k0;
      bcv[nt] = *(const bfrag*)(Cmb + cc);
      bgv[nt] = *(const bfrag*)(gwb + cc);
    }
#pragma unroll
    for (int mt = 0; mt < 2; ++mt)
#pragma unroll
      for (int nt = 0; nt < 2; ++nt) {
        ay[mt][nt] = mfma16(afv[mt], bcv[nt], ay[mt][nt]);
        ay[mt][nt] = mfma16(abv[mt], bcv[nt], ay[mt][nt]);
        az[mt][nt] = mfma16(axv[mt], bgv[nt], az[mt][nt]);
      }
  }
  float al = alpha[0];
#pragma unroll
  for (int mt = 0; mt < 2; ++mt)
#pragma unroll
    for (int nt = 0; nt < 2; ++nt)
#pragma unroll
      for (int q = 0; q < 4; ++q) {
        long grow = rb + mw*32 + mt*16 + lhi*4 + q;
        int  gcol = cb + nw*32 + nt*16 + l15;
        long t = grow >> 3, b = grow & 7;
        long o = (b * Nn + t) * Hn + gcol;
        float z = az[mt][nt][q] + gate_b[gcol];
        float g = 1.0f / (1.0f + __expf(-z));
        out[o] = x[o] + al * 0.5f * ay[mt][nt][q] * g;
      }
}

// ---------------------------------------------------------------------------
extern "C" void kernel_launch(void* const* d_in, const int* in_sizes, int n_in,
                              void* d_out, int out_size, void* d_ws, size_t ws_size,
                              hipStream_t stream) {
  const float* x     = (const float*)d_in[0];
  const float* scale = (const float*)d_in[1];
  const float* U     = (const float*)d_in[2];
  const float* V     = (const float*)d_in[3];
  const float* S     = (const float*)d_in[4];
  const float* Bm    = (const float*)d_in[5];
  const float* Cm    = (const float*)d_in[6];
  const float* gw    = (const float*)d_in[7];
  const float* gb    = (const float*)d_in[8];
  const float* alpha = (const float*)d_in[9];
  float* out = (float*)d_out;

  char* p = (char*)d_ws;
  auto alloc = [&](size_t sz) { char* r = p; p += (sz + 255) & ~(size_t)255; return r; };

  const size_t SZ_BF = (size_t)Nn * Bb * Hn * sizeof(unsigned short); // 25.2MB
  const size_t SZ_M  = (size_t)Hn * Hn * sizeof(float);               // 2.36MB
  const size_t SZ_MB = (size_t)Hn * Hn * sizeof(unsigned short);      // 1.18MB

  unsigned short* xn  = (unsigned short*)alloc(SZ_BF);
  unsigned short* u   = (unsigned short*)alloc(SZ_BF);   // later V16f
  unsigned short* VBb = (unsigned short*)alloc(SZ_BF);   // later V16b
  unsigned short* VAf = (unsigned short*)alloc(SZ_BF);   // later hf
  unsigned short* VAb = (unsigned short*)alloc(SZ_BF);   // later hb
  float* Af   = (float*)alloc(SZ_M);
  float* AfT  = (float*)alloc(SZ_M);
  float* P1   = (float*)alloc(SZ_M);
  float* P1T  = (float*)alloc(SZ_M);
  float* P2   = (float*)alloc(SZ_M);
  float* P2T  = (float*)alloc(SZ_M);
  unsigned short* Abf   = (unsigned short*)alloc(SZ_MB);
  unsigned short* A2b   = (unsigned short*)alloc(SZ_MB);
  unsigned short* A4b   = (unsigned short*)alloc(SZ_MB);
  unsigned short* A8b   = (unsigned short*)alloc(SZ_MB);
  unsigned short* A16b  = (unsigned short*)alloc(SZ_MB);
  unsigned short* A64b  = (unsigned short*)alloc(SZ_MB);
  unsigned short* A256b = (unsigned short*)alloc(SZ_MB);
  unsigned short* Bmb   = (unsigned short*)alloc(SZ_MB);
  unsigned short* Cmb   = (unsigned short*)alloc(SZ_MB);
  unsigned short* gwb   = (unsigned short*)alloc(SZ_MB);
  float* dresA   = (float*)alloc(Hn * sizeof(float));
  float* dres16  = (float*)alloc(Hn * sizeof(float));
  float* dres64  = (float*)alloc(Hn * sizeof(float));
  float* dres256 = (float*)alloc(Hn * sizeof(float));
  float* edge1 = (float*)alloc((size_t)32 * 256 * Hn * sizeof(float)); // 25.2MB
  float* edge2 = (float*)alloc((size_t)8  * 256 * Hn * sizeof(float)); // 6.3MB

  if ((size_t)(p - (char*)d_ws) > ws_size) return;  // workspace too small

  // prep
  k_abuild<<<dim3(768, 4), 256, 0, stream>>>(U, V, S, Bm, Cm, gw,
      Af, AfT, Abf, dresA, Bmb, Cmb, gwb);
  k_rms<<<4096, 256, 0, stream>>>(x, scale, xn);
  k_gemm_u<<<dim3(256, 6), 512, 0, stream>>>(xn, Bmb, u);

  // squaring chain: A2,A4,A8,A16,A32,A64,A128,A256
  k_sq<<<dim3(12, 6), 512, 0, stream>>>(Af, AfT, P1, P1T, A2b, nullptr);
  k_sq<<<dim3(12, 6), 512, 0, stream>>>(P1, P1T, P2, P2T, A4b, nullptr);
  k_sq<<<dim3(12, 6), 512, 0, stream>>>(P2, P2T, P1, P1T, A8b, nullptr);
  k_sq<<<dim3(12, 6), 512, 0, stream>>>(P1, P1T, P2, P2T, A16b, dres16);
  k_sq<<<dim3(12, 6), 512, 0, stream>>>(P2, P2T, P1, P1T, nullptr, nullptr);
  k_sq<<<dim3(12, 6), 512, 0, stream>>>(P1, P1T, P2, P2T, A64b, dres64);
  k_sq<<<dim3(12, 6), 512, 0, stream>>>(P2, P2T, P1, P1T, nullptr, nullptr);
  k_sq<<<dim3(12, 6), 512, 0, stream>>>(P1, P1T, P2, P2T, A256b, dres256);

  // V-doubling: u -> V2 (VA) -> V4 (u,VBb) -> V8 (VA) -> V16 (u,VBb)
  k_dbl<<<dim3(512, 6), 512, 0, stream>>>(u,   u,   VAf, VAb, Abf, 8);
  k_dbl<<<dim3(512, 6), 512, 0, stream>>>(VAf, VAb, u,   VBb, A2b, 16);
  k_dbl<<<dim3(512, 6), 512, 0, stream>>>(u,   VBb, VAf, VAb, A4b, 32);
  k_dbl<<<dim3(512, 6), 512, 0, stream>>>(VAf, VAb, u,   VBb, A8b, 64);
  // V16f = u, V16b = VBb; VAf/VAb free -> become hf/hb

  // scans
  k_scanL1<<<256, 512, 0, stream>>>(A16b, dres16, u, VBb,
      nullptr, nullptr, nullptr, edge1);
  k_scanE<<<64, 512, 0, stream>>>(A64b, dres64, edge1, nullptr, edge2, 4, 0);
  k_scanE<<<8,  512, 0, stream>>>(A256b, dres256, edge2, nullptr, nullptr, 8, 1);
  k_scanE<<<64, 512, 0, stream>>>(A64b, dres64, edge1, edge2, nullptr, 4, 1);
  k_scanL1<<<256, 512, 0, stream>>>(A16b, dres16, u, VBb,
      edge1, VAf, VAb, nullptr);

  k_final<<<dim3(256, 6), 512, 0, stream>>>(xn, VAf, VAb, Cmb, gwb, gb, alpha, x, out);
}

// Round 4
// 2845.361 us; speedup vs baseline: 1.2469x; 1.2469x over previous
//
#include <hip/hip_runtime.h>

// ---------------------------------------------------------------------------
// BiSSM global block, MI355X — round 4: scan eliminated via full log-doubling.
//   X_2[t]  = xn[t]@Bm^T + xn[t-/+1]@(A@Bm)^T          (MODE1 dual-stream GEMM)
//   X_2k[t] = X_k[t] + X_k[t-/+k]@(A^k)^T   k=2..1024   (MODE0 shift-GEMM x10)
//   out     = x + alpha*0.5*((Xf+Xb)@Cm^T)*sigmoid(xn@gw^T+gb)  (MODE2)
// Powers A^2..A^1024 from hi/lo-bf16 f32 squaring chain (10x k_sq).
// GEMM: 128x128xBK64 tile, A coalesced-staged to padded LDS [128][72]
// (bank-balanced), B read direct from L2 (1.18MB resident), wave=32x128,
// XCD-swizzled col-fast grid for A-panel L2 reuse.
// ---------------------------------------------------------------------------

typedef short  bfrag __attribute__((ext_vector_type(8)));   // 8 x bf16
typedef float  ffrag __attribute__((ext_vector_type(4)));   // mfma acc
typedef float  f4    __attribute__((ext_vector_type(4)));

#define DEV static __device__ __forceinline__
#define Hn 768

DEV unsigned short f2bf(float f) {
  unsigned u = __float_as_uint(f);
  u += 0x7fffu + ((u >> 16) & 1u);            // round-to-nearest-even
  return (unsigned short)(u >> 16);
}
DEV float bf2f(unsigned short s) { return __uint_as_float(((unsigned)s) << 16); }

DEV ffrag mfma16(bfrag a, bfrag b, ffrag c) {
  return __builtin_amdgcn_mfma_f32_16x16x32_bf16(a, b, c, 0, 0, 0);
}

union BF8 { bfrag v; unsigned short u[8]; };

// ---------------------------------------------------------------------------
// k_abuild: gridDim = (768, 4); task = blockIdx.y
//   0: A row i (f32 rm+tr, bf16) ; block i==0 also zeroes zp
//   1: Bm -> Bmb (rm) + BmTb (transposed) ; 2: Cm -> Cmb ; 3: gw -> gwb
__global__ __launch_bounds__(256) void k_abuild(
    const float* __restrict__ U, const float* __restrict__ V,
    const float* __restrict__ S, const float* __restrict__ Bm,
    const float* __restrict__ Cm, const float* __restrict__ gw,
    float* __restrict__ Af, float* __restrict__ AfT,
    unsigned short* __restrict__ Abf,
    unsigned short* __restrict__ Bmb, unsigned short* __restrict__ BmTb,
    unsigned short* __restrict__ Cmb, unsigned short* __restrict__ gwb,
    unsigned short* __restrict__ zp) {
  int i = blockIdx.x;
  int task = blockIdx.y;
  if (task == 0) {
    float u0 = U[i*4+0], u1 = U[i*4+1], u2 = U[i*4+2], u3 = U[i*4+3];
    for (int j = threadIdx.x; j < Hn; j += 256) {
      float a = u0*V[j*4+0] + u1*V[j*4+1] + u2*V[j*4+2] + u3*V[j*4+3]
              + S[i*Hn+j] - S[j*Hn+i];
      if (i == j) a += -(float)(i+1) / 768.0f;
      Af[i*Hn+j]  = a;
      AfT[j*Hn+i] = a;
      Abf[i*Hn+j] = f2bf(a);
    }
    if (i == 0) for (int j = threadIdx.x; j < 512; j += 256) zp[j] = 0;
  } else if (task == 1) {
    for (int j = threadIdx.x; j < Hn; j += 256) {
      unsigned short v = f2bf(Bm[i*Hn+j]);
      Bmb[i*Hn+j]  = v;
      BmTb[j*Hn+i] = v;
    }
  } else {
    const float* src = (task==2) ? Cm : gw;
    unsigned short* dst = (task==2) ? Cmb : gwb;
    for (int j = threadIdx.x; j < Hn; j += 256) dst[i*Hn+j] = f2bf(src[i*Hn+j]);
  }
}

// ---------------------------------------------------------------------------
// k_rms: one wave per row (row = b*2048 + t); write xn in (t,b) order, bf16.
__global__ __launch_bounds__(256) void k_rms(
    const float* __restrict__ x, const float* __restrict__ scale,
    unsigned short* __restrict__ xn) {
  int row  = blockIdx.x * 4 + (threadIdx.x >> 6);
  int lane = threadIdx.x & 63;
  int b = row >> 11, t = row & 2047;
  const float* xr = x + (long)row * Hn;
  float v[12];
  float ss = 0.f;
#pragma unroll
  for (int j = 0; j < 12; ++j) { v[j] = xr[lane + j*64]; ss += v[j]*v[j]; }
#pragma unroll
  for (int off = 1; off < 64; off <<= 1) ss += __shfl_xor(ss, off);
  float inv = 1.0f / sqrtf(ss / 768.0f + 1e-8f);
  unsigned short* dst = xn + ((long)t * 8 + b) * Hn;
#pragma unroll
  for (int j = 0; j < 12; ++j) dst[lane + j*64] = f2bf(v[j] * inv * scale[lane + j*64]);
}

// ---------------------------------------------------------------------------
// k_sq: Z = X @ X, hi/lo bf16 (3 passes). Writes Z rm + Z^T rm f32 + bf16.
// grid (12, 6), 512 thr, tile 64x128.
__global__ __launch_bounds__(512) void k_sq(
    const float* __restrict__ X, const float* __restrict__ XT,
    float* __restrict__ Z, float* __restrict__ ZT,
    unsigned short* __restrict__ Zbf) {
  int tid = threadIdx.x, lane = tid & 63, w = tid >> 6;
  int mw = w >> 2, nw = w & 3, l15 = lane & 15, lhi = lane >> 4;
  int rb = blockIdx.x * 64, cb = blockIdx.y * 128;
  ffrag acc[2][2] = {};
  for (int kt = 0; kt < 24; ++kt) {
    int k0 = kt*32 + lhi*8;
    BF8 ah[2], al[2], bh[2], bl[2];
#pragma unroll
    for (int mt = 0; mt < 2; ++mt) {
      const f4* p = (const f4*)(X + (long)(rb + mw*32 + mt*16 + l15) * Hn + k0);
      f4 x0 = p[0], x1 = p[1];
#pragma unroll
      for (int j = 0; j < 8; ++j) {
        float f = (j < 4) ? x0[j] : x1[j-4];
        unsigned short h = f2bf(f);
        ah[mt].u[j] = h; al[mt].u[j] = f2bf(f - bf2f(h));
      }
    }
#pragma unroll
    for (int nt = 0; nt < 2; ++nt) {
      const f4* p = (const f4*)(XT + (long)(cb + nw*32 + nt*16 + l15) * Hn + k0);
      f4 x0 = p[0], x1 = p[1];
#pragma unroll
      for (int j = 0; j < 8; ++j) {
        float f = (j < 4) ? x0[j] : x1[j-4];
        unsigned short h = f2bf(f);
        bh[nt].u[j] = h; bl[nt].u[j] = f2bf(f - bf2f(h));
      }
    }
#pragma unroll
    for (int mt = 0; mt < 2; ++mt)
#pragma unroll
      for (int nt = 0; nt < 2; ++nt) {
        acc[mt][nt] = mfma16(ah[mt].v, bh[nt].v, acc[mt][nt]);
        acc[mt][nt] = mfma16(ah[mt].v, bl[nt].v, acc[mt][nt]);
        acc[mt][nt] = mfma16(al[mt].v, bh[nt].v, acc[mt][nt]);
      }
  }
#pragma unroll
  for (int mt = 0; mt < 2; ++mt)
#pragma unroll
    for (int nt = 0; nt < 2; ++nt)
#pragma unroll
      for (int q = 0; q < 4; ++q) {
        int grow = rb + mw*32 + mt*16 + lhi*4 + q;
        int gcol = cb + nw*32 + nt*16 + l15;
        float vv = acc[mt][nt][q];
        Z[(long)grow*Hn + gcol] = vv;
        ZT[(long)gcol*Hn + grow] = vv;
        Zbf[(long)grow*Hn + gcol] = f2bf(vv);
      }
}

// ---------------------------------------------------------------------------
// k_gemm<MODE>: 128x128 tile, BK=64, 4 waves (each 32 rows x 128 cols).
// A-stream(s) staged into LDS [128][72] (pad -> bank-balanced); B direct L2.
// MODE 0: out = res? + A0[r+sh] @ B0      (doubling level / Bm2 build)
// MODE 1: out = A0[idx] @ B0 + A0[idx-/+8] @ B1        (X2 from xn)
// MODE 2: outf = x + alpha*0.5*((A0+A1)@B0) * sigmoid(A2@B1 + gb)
__global__ __launch_bounds__(256) void k_gemm_impl_dummy() {}

template<int MODE>
__global__ __launch_bounds__(256) void k_gemm(
    const unsigned short* __restrict__ A0s, const unsigned short* __restrict__ A1s,
    const unsigned short* __restrict__ A2s,
    const unsigned short* __restrict__ B0s, const unsigned short* __restrict__ B1s,
    const unsigned short* __restrict__ res,
    unsigned short* __restrict__ outb,
    const unsigned short* __restrict__ zp,
    int rows_half, int shf, int shb, int ncol,
    const float* __restrict__ gb, const float* __restrict__ alpha,
    const float* __restrict__ x, float* __restrict__ outf) {
  constexpr int NS = (MODE == 0) ? 1 : (MODE == 1) ? 2 : 3;
  __shared__ unsigned short lds[NS][128][72];
  const int tid = threadIdx.x, lane = tid & 63, w = tid >> 6;
  const int l15 = lane & 15, lhi = lane >> 4;

  // XCD-aware bijective swizzle (m204) on the flat grid; col-fast decompose.
  const int nwg = gridDim.x, fblk = blockIdx.x;
  const int q8 = nwg >> 3, r8 = nwg & 7, xcd = fblk & 7, fo = fblk >> 3;
  const int wg = (xcd < r8 ? xcd*(q8+1) : r8*(q8+1) + (xcd-r8)*q8) + fo;
  const int cb = wg % ncol, rb = wg / ncol;
  const long r0 = (long)rb * 128;
  const int dir = (int)(r0 >= rows_half);

  bfrag rg[NS][4];
  const int srl = tid >> 3, sc16 = tid & 7;   // staging: row-lane, col16

  auto stage_load = [&](int kt) {
#pragma unroll
    for (int i = 0; i < 4; ++i) {
      long r = r0 + i*32 + srl;
#pragma unroll
      for (int s = 0; s < NS; ++s) {
        long gr; const unsigned short* src; bool ok = true;
        if (MODE == 0) {
          gr = r + (dir ? shb : shf); src = A0s;
          ok = (gr >= (long)dir*rows_half) && (gr < (long)(dir+1)*rows_half);
        } else if (MODE == 1) {
          long idx = r - (long)dir*rows_half;
          gr = idx + (s == 0 ? 0 : (dir ? 8 : -8)); src = A0s;
          ok = (gr >= 0) && (gr < rows_half);
        } else {
          gr = r; src = (s == 0) ? A0s : (s == 1) ? A1s : A2s;
        }
        const unsigned short* p = ok ? (src + gr*Hn + kt*64 + sc16*8)
                                     : (zp + sc16*8);
        rg[s][i] = *(const bfrag*)p;
      }
    }
  };

  ffrag acc[2][8] = {};
  ffrag accZ[(MODE == 2) ? 2 : 1][(MODE == 2) ? 8 : 1] = {};

  stage_load(0);
  for (int kt = 0; kt < 12; ++kt) {
    __syncthreads();     // prior iteration's LDS reads complete
#pragma unroll
    for (int i = 0; i < 4; ++i)
#pragma unroll
      for (int s = 0; s < NS; ++s)
        *(bfrag*)&lds[s][i*32 + srl][sc16*8] = rg[s][i];
    __syncthreads();     // staged tile visible
    if (kt < 11) stage_load(kt + 1);   // overlaps with compute below

    const long bc0 = (long)cb * 128;
#pragma unroll
    for (int kk = 0; kk < 2; ++kk) {
      const int ko = kk*32 + lhi*8;
      bfrag a[NS][2];
#pragma unroll
      for (int s = 0; s < NS; ++s)
#pragma unroll
        for (int mt = 0; mt < 2; ++mt)
          a[s][mt] = *(const bfrag*)&lds[s][w*32 + mt*16 + l15][ko];
#pragma unroll
      for (int nh = 0; nh < 2; ++nh) {
        bfrag b0[4], b1[4];
#pragma unroll
        for (int nt = 0; nt < 4; ++nt) {
          long n = bc0 + nh*64 + nt*16 + l15;
          b0[nt] = *(const bfrag*)(B0s + n*Hn + kt*64 + ko);
          if (MODE >= 1) b1[nt] = *(const bfrag*)(B1s + n*Hn + kt*64 + ko);
        }
#pragma unroll
        for (int mt = 0; mt < 2; ++mt)
#pragma unroll
          for (int nt = 0; nt < 4; ++nt) {
            const int nn = nh*4 + nt;
            if (MODE == 0) {
              acc[mt][nn] = mfma16(a[0][mt], b0[nt], acc[mt][nn]);
            } else if (MODE == 1) {
              acc[mt][nn] = mfma16(a[0][mt], b0[nt], acc[mt][nn]);
              acc[mt][nn] = mfma16(a[1][mt], b1[nt], acc[mt][nn]);
            } else {
              acc[mt][nn]  = mfma16(a[0][mt], b0[nt], acc[mt][nn]);
              acc[mt][nn]  = mfma16(a[1][mt], b0[nt], acc[mt][nn]);
              accZ[mt][nn] = mfma16(a[2][mt], b1[nt], accZ[mt][nn]);
            }
          }
      }
    }
  }

  const long bc0 = (long)cb * 128;
  const float al = (MODE == 2) ? alpha[0] : 0.f;
#pragma unroll
  for (int mt = 0; mt < 2; ++mt)
#pragma unroll
    for (int nn = 0; nn < 8; ++nn)
#pragma unroll
      for (int q = 0; q < 4; ++q) {
        long grow = r0 + w*32 + mt*16 + lhi*4 + q;
        long gcol = bc0 + nn*16 + l15;
        float v = acc[mt][nn][q];
        if (MODE == 0) {
          if (res) v += bf2f(res[grow*Hn + gcol]);
          outb[grow*Hn + gcol] = f2bf(v);
        } else if (MODE == 1) {
          outb[grow*Hn + gcol] = f2bf(v);
        } else {
          float z = accZ[mt][nn][q] + gb[gcol];
          float g = 1.0f / (1.0f + __expf(-z));
          long t = grow >> 3, b = grow & 7;
          long o = (b*2048 + t)*Hn + gcol;
          outf[o] = x[o] + al * 0.5f * v * g;
        }
      }
}

// ---------------------------------------------------------------------------
extern "C" void kernel_launch(void* const* d_in, const int* in_sizes, int n_in,
                              void* d_out, int out_size, void* d_ws, size_t ws_size,
                              hipStream_t stream) {
  const float* x     = (const float*)d_in[0];
  const float* scale = (const float*)d_in[1];
  const float* U     = (const float*)d_in[2];
  const float* V     = (const float*)d_in[3];
  const float* S     = (const float*)d_in[4];
  const float* Bm    = (const float*)d_in[5];
  const float* Cm    = (const float*)d_in[6];
  const float* gw    = (const float*)d_in[7];
  const float* gb    = (const float*)d_in[8];
  const float* alpha = (const float*)d_in[9];
  float* out = (float*)d_out;

  char* p = (char*)d_ws;
  auto alloc = [&](size_t sz) { char* r = p; p += (sz + 255) & ~(size_t)255; return r; };

  const size_t SZ_X  = (size_t)32768 * Hn * sizeof(unsigned short);  // 50.3MB
  const size_t SZ_BF = (size_t)16384 * Hn * sizeof(unsigned short);  // 25.2MB
  const size_t SZ_M  = (size_t)Hn * Hn * sizeof(float);              // 2.36MB
  const size_t SZ_MB = (size_t)Hn * Hn * sizeof(unsigned short);     // 1.18MB

  unsigned short* xn = (unsigned short*)alloc(SZ_BF);
  unsigned short* XA = (unsigned short*)alloc(SZ_X);
  unsigned short* XB = (unsigned short*)alloc(SZ_X);
  float* Af  = (float*)alloc(SZ_M);
  float* AfT = (float*)alloc(SZ_M);
  float* P1  = (float*)alloc(SZ_M);
  float* P1T = (float*)alloc(SZ_M);
  float* P2  = (float*)alloc(SZ_M);
  float* P2T = (float*)alloc(SZ_M);
  unsigned short* Abf = (unsigned short*)alloc(SZ_MB);
  unsigned short* Ab[10];                      // A^2..A^1024 bf16
  for (int i = 0; i < 10; ++i) Ab[i] = (unsigned short*)alloc(SZ_MB);
  unsigned short* Bmb  = (unsigned short*)alloc(SZ_MB);
  unsigned short* BmTb = (unsigned short*)alloc(SZ_MB);
  unsigned short* Cmb  = (unsigned short*)alloc(SZ_MB);
  unsigned short* gwb  = (unsigned short*)alloc(SZ_MB);
  unsigned short* Bm2b = (unsigned short*)alloc(SZ_MB);
  unsigned short* zp   = (unsigned short*)alloc(512 * sizeof(unsigned short));

  if ((size_t)(p - (char*)d_ws) > ws_size) return;  // workspace too small

  k_abuild<<<dim3(768, 4), 256, 0, stream>>>(U, V, S, Bm, Cm, gw,
      Af, AfT, Abf, Bmb, BmTb, Cmb, gwb, zp);
  k_rms<<<4096, 256, 0, stream>>>(x, scale, xn);

  // squaring chain: A -> A^2 -> ... -> A^1024 (bf16 emitted each step)
  const float* sx = Af; const float* sxt = AfT;
  float* za = P1; float* zat = P1T; float* zb = P2; float* zbt = P2T;
  for (int i = 0; i < 10; ++i) {
    k_sq<<<dim3(12, 6), 512, 0, stream>>>(sx, sxt, za, zat, Ab[i]);
    sx = za; sxt = zat;
    float* t1 = za; float* t2 = zat; za = zb; zat = zbt; zb = t1; zbt = t2;
  }

  // Bm2 = A @ Bm  (bf16): sum_k A[m,k]*BmT[n,k]
  k_gemm<0><<<36, 256, 0, stream>>>(Abf, nullptr, nullptr, BmTb, nullptr,
      nullptr, Bm2b, zp, 768, 0, 0, 6, nullptr, nullptr, nullptr, nullptr);

  // X2 = xn@Bm^T + xn[t-/+1]@Bm2^T   (32768 rows: fwd | bwd)
  k_gemm<1><<<1536, 256, 0, stream>>>(xn, nullptr, nullptr, Bmb, Bm2b,
      nullptr, XA, zp, 16384, 0, 0, 6, nullptr, nullptr, nullptr, nullptr);

  // doubling levels: X4..X2048
  unsigned short* src = XA; unsigned short* dst = XB;
  for (int i = 0; i < 10; ++i) {
    int sh = 8 << (i + 1);   // 8*2^(i+1) rows = 2^(i+1) timesteps
    k_gemm<0><<<1536, 256, 0, stream>>>(src, nullptr, nullptr, Ab[i], nullptr,
        src, dst, zp, 16384, -sh, sh, 6, nullptr, nullptr, nullptr, nullptr);
    unsigned short* t = src; src = dst; dst = t;
  }

  // final: out = x + alpha*0.5*((Xf+Xb)@Cm^T)*sigmoid(xn@gw^T+gb)
  k_gemm<2><<<768, 256, 0, stream>>>(src, src + (size_t)16384*Hn, xn,
      Cmb, gwb, nullptr, nullptr, zp, 16384, 0, 0, 6, gb, alpha, x, out);
}

// Round 5
// 1597.942 us; speedup vs baseline: 2.2203x; 1.7806x over previous
//
#include <hip/hip_runtime.h>

// ---------------------------------------------------------------------------
// BiSSM global block, MI355X — round 5: log-doubling with m97-style GEMM.
//   u[t]    = xn[t]@Bm^T (written to fwd+bwd halves)        k_gemm<0> dup=1
//   X_2k[t] = X_k[t] + X_k[t-/+k]@(A^k)^T, k=1..512          k_gemm<0> x10
//   Xsum[t] = X_f[t]+X_f[t-1024]@W + X_b[t]+X_b[t+1024]@W    k_gemm<1> (W=A^1024)
//   y       = Xsum@Cm^T                                      k_gemm<0>
//   out     = x + alpha*0.5*y*sigmoid(xn@gw^T+gb)            k_gemm<2>
// GEMM core: 128x128 tile, BK=64, 4 waves (64x64, 4x4 frags), A+B staged via
// global_load_lds(16B) with T2 swizzle (linear LDS dest, source chunk c^(r&7),
// swizzled ds_read) -> bank-conflict-free. OOB rows clamp source to zero page.
// Powers A^2..A^1024: hi/lo-bf16 f32 squaring chain (k_sq x10).
// ---------------------------------------------------------------------------

typedef short  bfrag __attribute__((ext_vector_type(8)));   // 8 x bf16
typedef float  ffrag __attribute__((ext_vector_type(4)));   // mfma acc
typedef float  f4    __attribute__((ext_vector_type(4)));

#define DEV static __device__ __forceinline__
#define Hn 768

DEV unsigned short f2bf(float f) {
  unsigned u = __float_as_uint(f);
  u += 0x7fffu + ((u >> 16) & 1u);            // round-to-nearest-even
  return (unsigned short)(u >> 16);
}
DEV float bf2f(unsigned short s) { return __uint_as_float(((unsigned)s) << 16); }

DEV ffrag mfma16(bfrag a, bfrag b, ffrag c) {
  return __builtin_amdgcn_mfma_f32_16x16x32_bf16(a, b, c, 0, 0, 0);
}

DEV void glds16(const unsigned short* g, unsigned short* l) {
  __builtin_amdgcn_global_load_lds(
      (const __attribute__((address_space(1))) unsigned int*)g,
      (__attribute__((address_space(3))) unsigned int*)l, 16, 0, 0);
}

union BF8 { bfrag v; unsigned short u[8]; };

// ---------------------------------------------------------------------------
// k_abuild: gridDim = (768, 4); task = blockIdx.y
__global__ __launch_bounds__(256) void k_abuild(
    const float* __restrict__ U, const float* __restrict__ V,
    const float* __restrict__ S, const float* __restrict__ Bm,
    const float* __restrict__ Cm, const float* __restrict__ gw,
    float* __restrict__ Af, float* __restrict__ AfT,
    unsigned short* __restrict__ Abf,
    unsigned short* __restrict__ Bmb, unsigned short* __restrict__ Cmb,
    unsigned short* __restrict__ gwb, unsigned short* __restrict__ zp) {
  int i = blockIdx.x;
  int task = blockIdx.y;
  if (task == 0) {
    float u0 = U[i*4+0], u1 = U[i*4+1], u2 = U[i*4+2], u3 = U[i*4+3];
    for (int j = threadIdx.x; j < Hn; j += 256) {
      float a = u0*V[j*4+0] + u1*V[j*4+1] + u2*V[j*4+2] + u3*V[j*4+3]
              + S[i*Hn+j] - S[j*Hn+i];
      if (i == j) a += -(float)(i+1) / 768.0f;
      Af[i*Hn+j]  = a;
      AfT[j*Hn+i] = a;
      Abf[i*Hn+j] = f2bf(a);
    }
    if (i == 0) for (int j = threadIdx.x; j < 1024; j += 256) zp[j] = 0;
  } else {
    const float* src = (task==1) ? Bm : (task==2) ? Cm : gw;
    unsigned short* dst = (task==1) ? Bmb : (task==2) ? Cmb : gwb;
    for (int j = threadIdx.x; j < Hn; j += 256) dst[i*Hn+j] = f2bf(src[i*Hn+j]);
  }
}

// ---------------------------------------------------------------------------
// k_rms: one wave per row (row = b*2048 + t); write xn in (t,b) order, bf16.
__global__ __launch_bounds__(256) void k_rms(
    const float* __restrict__ x, const float* __restrict__ scale,
    unsigned short* __restrict__ xn) {
  int row  = blockIdx.x * 4 + (threadIdx.x >> 6);
  int lane = threadIdx.x & 63;
  int b = row >> 11, t = row & 2047;
  const float* xr = x + (long)row * Hn;
  float v[12];
  float ss = 0.f;
#pragma unroll
  for (int j = 0; j < 12; ++j) { v[j] = xr[lane + j*64]; ss += v[j]*v[j]; }
#pragma unroll
  for (int off = 1; off < 64; off <<= 1) ss += __shfl_xor(ss, off);
  float inv = 1.0f / sqrtf(ss / 768.0f + 1e-8f);
  unsigned short* dst = xn + ((long)t * 8 + b) * Hn;
#pragma unroll
  for (int j = 0; j < 12; ++j) dst[lane + j*64] = f2bf(v[j] * inv * scale[lane + j*64]);
}

// ---------------------------------------------------------------------------
// k_sq: Z = X @ X, hi/lo bf16 (3 passes). Writes Z rm + Z^T rm f32 + bf16.
// grid (12, 6), 512 thr, tile 64x128.
__global__ __launch_bounds__(512) void k_sq(
    const float* __restrict__ X, const float* __restrict__ XT,
    float* __restrict__ Z, float* __restrict__ ZT,
    unsigned short* __restrict__ Zbf) {
  int tid = threadIdx.x, lane = tid & 63, w = tid >> 6;
  int mw = w >> 2, nw = w & 3, l15 = lane & 15, lhi = lane >> 4;
  int rb = blockIdx.x * 64, cb = blockIdx.y * 128;
  ffrag acc[2][2] = {};
  for (int kt = 0; kt < 24; ++kt) {
    int k0 = kt*32 + lhi*8;
    BF8 ah[2], al[2], bh[2], bl[2];
#pragma unroll
    for (int mt = 0; mt < 2; ++mt) {
      const f4* p = (const f4*)(X + (long)(rb + mw*32 + mt*16 + l15) * Hn + k0);
      f4 x0 = p[0], x1 = p[1];
#pragma unroll
      for (int j = 0; j < 8; ++j) {
        float f = (j < 4) ? x0[j] : x1[j-4];
        unsigned short h = f2bf(f);
        ah[mt].u[j] = h; al[mt].u[j] = f2bf(f - bf2f(h));
      }
    }
#pragma unroll
    for (int nt = 0; nt < 2; ++nt) {
      const f4* p = (const f4*)(XT + (long)(cb + nw*32 + nt*16 + l15) * Hn + k0);
      f4 x0 = p[0], x1 = p[1];
#pragma unroll
      for (int j = 0; j < 8; ++j) {
        float f = (j < 4) ? x0[j] : x1[j-4];
        unsigned short h = f2bf(f);
        bh[nt].u[j] = h; bl[nt].u[j] = f2bf(f - bf2f(h));
      }
    }
#pragma unroll
    for (int mt = 0; mt < 2; ++mt)
#pragma unroll
      for (int nt = 0; nt < 2; ++nt) {
        acc[mt][nt] = mfma16(ah[mt].v, bh[nt].v, acc[mt][nt]);
        acc[mt][nt] = mfma16(ah[mt].v, bl[nt].v, acc[mt][nt]);
        acc[mt][nt] = mfma16(al[mt].v, bh[nt].v, acc[mt][nt]);
      }
  }
#pragma unroll
  for (int mt = 0; mt < 2; ++mt)
#pragma unroll
    for (int nt = 0; nt < 2; ++nt)
#pragma unroll
      for (int q = 0; q < 4; ++q) {
        int grow = rb + mw*32 + mt*16 + lhi*4 + q;
        int gcol = cb + nw*32 + nt*16 + l15;
        float vv = acc[mt][nt][q];
        Z[(long)grow*Hn + gcol] = vv;
        ZT[(long)gcol*Hn + grow] = vv;
        Zbf[(long)grow*Hn + gcol] = f2bf(vv);
      }
}

// ---------------------------------------------------------------------------
// k_gemm<MODE>: 128x128 tile, BK=64, 256 thr (4 waves, 2x2 of 64x64).
// A(+streams) and B staged via global_load_lds with T2 swizzle.
// MODE 0: outb = [res +] A0[row -/+ sh] @ B0^T ; dup -> also write +16384.
// MODE 1: outb[r] = res[r]+res[r+16384] + (A0[r-sh] + A0[r+16384+sh]) @ B0^T
// MODE 2: outf = x + alpha*0.5*yb*sigmoid(A0@B0^T + gb)   (row = t*8+b)
template<int MODE>
__global__ __launch_bounds__(256) void k_gemm(
    const unsigned short* __restrict__ A0s, const unsigned short* __restrict__ B0s,
    const unsigned short* __restrict__ res, unsigned short* __restrict__ outb,
    const unsigned short* __restrict__ zp, int sh, int dup,
    const unsigned short* __restrict__ yb,
    const float* __restrict__ gb, const float* __restrict__ alpha,
    const float* __restrict__ x, float* __restrict__ outf) {
  constexpr int NS = (MODE == 1) ? 2 : 1;
  __shared__ unsigned short ldsA[NS][128*64];
  __shared__ unsigned short ldsB[128*64];

  const int tid = threadIdx.x, lane = tid & 63, w = tid >> 6;
  const int l15 = lane & 15, lhi = lane >> 4;
  const int wr = w >> 1, wc = w & 1;

  // XCD-aware bijective block swizzle (m204), col-fast decompose (ncol=6).
  const int nwg = gridDim.x;
  const int q8 = nwg >> 3, r8 = nwg & 7, xcd = blockIdx.x & 7, fo = blockIdx.x >> 3;
  const int wg = (xcd < r8 ? xcd*(q8+1) : r8*(q8+1) + (xcd - r8)*q8) + fo;
  const int cb = wg % 6, rbk = wg / 6;
  const long r0 = (long)rbk * 128;
  const long bc0 = (long)cb * 128;
  const int dir = (MODE == 0) ? (r0 >= 16384 ? 1 : 0) : 0;

  bool skip = false;
  if (MODE == 0 && sh > 0)
    skip = dir ? (r0 >= 32768 - sh) : (r0 + 128 <= sh);

  // staging geometry: wave w covers rows w*32..w*32+31; inst j covers 8 rows.
  const int srow = w*32 + (lane >> 3);
  const int cs = lane & 7;
  int offA[NS][4]; bool vA[NS][4]; int offB[4];
#pragma unroll
  for (int j = 0; j < 4; ++j) {
    const int r = srow + j*8;
    const int c = cs ^ (r & 7);          // inverse swizzle on source chunk
    if (MODE == 0) {
      long gr = r0 + r + (dir ? sh : -sh);
      vA[0][j] = dir ? (gr < 32768) : (gr >= 0);
      offA[0][j] = (int)(gr * Hn + c*8);
    } else if (MODE == 1) {
      long g0 = r0 + r - sh;
      vA[0][j] = (g0 >= 0);            offA[0][j] = (int)(g0 * Hn + c*8);
      long g1 = r0 + r + 16384 + sh;
      vA[1][j] = (g1 < 32768);         offA[1][j] = (int)(g1 * Hn + c*8);
    } else {
      vA[0][j] = true;                 offA[0][j] = (int)((r0 + r) * Hn + c*8);
    }
    offB[j] = (int)((bc0 + r) * Hn + c*8);
  }

  ffrag acc[4][4] = {};
  if (!skip) {
    for (int kt = 0; kt < 12; ++kt) {
      const int ko = kt*64;
#pragma unroll
      for (int j = 0; j < 4; ++j) {
#pragma unroll
        for (int s = 0; s < NS; ++s) {
          const unsigned short* g = vA[s][j] ? (A0s + offA[s][j] + ko) : zp;
          glds16(g, &ldsA[s][(w*4 + j) * 512]);
        }
        glds16(B0s + offB[j] + ko, &ldsB[(w*4 + j) * 512]);
      }
      __syncthreads();     // drains vmcnt; staged tile visible
#pragma unroll
      for (int kk = 0; kk < 2; ++kk) {
        const int cx = ((kk*4 + lhi) ^ (l15 & 7)) * 8;   // swizzled read chunk
        bfrag a[NS][4], b[4];
#pragma unroll
        for (int mt = 0; mt < 4; ++mt) {
          const int row = wr*64 + mt*16 + l15;
#pragma unroll
          for (int s = 0; s < NS; ++s)
            a[s][mt] = *(const bfrag*)&ldsA[s][row*64 + cx];
        }
#pragma unroll
        for (int nt = 0; nt < 4; ++nt) {
          const int row = wc*64 + nt*16 + l15;
          b[nt] = *(const bfrag*)&ldsB[row*64 + cx];
        }
#pragma unroll
        for (int mt = 0; mt < 4; ++mt)
#pragma unroll
          for (int nt = 0; nt < 4; ++nt) {
            acc[mt][nt] = mfma16(a[0][mt], b[nt], acc[mt][nt]);
            if (NS == 2) acc[mt][nt] = mfma16(a[1][mt], b[nt], acc[mt][nt]);
          }
      }
      __syncthreads();     // all LDS reads done before next stage overwrites
    }
  }

  const float al = (MODE == 2) ? alpha[0] : 0.f;
#pragma unroll
  for (int mt = 0; mt < 4; ++mt)
#pragma unroll
    for (int nt = 0; nt < 4; ++nt)
#pragma unroll
      for (int q = 0; q < 4; ++q) {
        const long grow = r0 + wr*64 + mt*16 + lhi*4 + q;
        const long gcol = bc0 + wc*64 + nt*16 + l15;
        float v = acc[mt][nt][q];
        if (MODE == 0) {
          if (res) v += bf2f(res[grow*Hn + gcol]);
          unsigned short hv = f2bf(v);
          outb[grow*Hn + gcol] = hv;
          if (dup) outb[(grow + 16384)*Hn + gcol] = hv;
        } else if (MODE == 1) {
          v += bf2f(res[grow*Hn + gcol]) + bf2f(res[(grow + 16384)*Hn + gcol]);
          outb[grow*Hn + gcol] = f2bf(v);
        } else {
          float z = v + gb[gcol];
          float g = 1.0f / (1.0f + __expf(-z));
          float y = bf2f(yb[grow*Hn + gcol]);
          long t = grow >> 3, b = grow & 7;
          long o = (b*2048 + t)*Hn + gcol;
          outf[o] = x[o] + al * 0.5f * y * g;
        }
      }
}

// ---------------------------------------------------------------------------
extern "C" void kernel_launch(void* const* d_in, const int* in_sizes, int n_in,
                              void* d_out, int out_size, void* d_ws, size_t ws_size,
                              hipStream_t stream) {
  const float* x     = (const float*)d_in[0];
  const float* scale = (const float*)d_in[1];
  const float* U     = (const float*)d_in[2];
  const float* V     = (const float*)d_in[3];
  const float* S     = (const float*)d_in[4];
  const float* Bm    = (const float*)d_in[5];
  const float* Cm    = (const float*)d_in[6];
  const float* gw    = (const float*)d_in[7];
  const float* gb    = (const float*)d_in[8];
  const float* alpha = (const float*)d_in[9];
  float* out = (float*)d_out;

  char* p = (char*)d_ws;
  auto alloc = [&](size_t sz) { char* r = p; p += (sz + 255) & ~(size_t)255; return r; };

  const size_t SZ_X  = (size_t)32768 * Hn * sizeof(unsigned short);  // 50.3MB
  const size_t SZ_BF = (size_t)16384 * Hn * sizeof(unsigned short);  // 25.2MB
  const size_t SZ_M  = (size_t)Hn * Hn * sizeof(float);              // 2.36MB
  const size_t SZ_MB = (size_t)Hn * Hn * sizeof(unsigned short);     // 1.18MB

  unsigned short* xn = (unsigned short*)alloc(SZ_BF);
  unsigned short* XA = (unsigned short*)alloc(SZ_X);
  unsigned short* XB = (unsigned short*)alloc(SZ_X);
  float* Af  = (float*)alloc(SZ_M);
  float* AfT = (float*)alloc(SZ_M);
  float* P1  = (float*)alloc(SZ_M);
  float* P1T = (float*)alloc(SZ_M);
  float* P2  = (float*)alloc(SZ_M);
  float* P2T = (float*)alloc(SZ_M);
  unsigned short* Abf = (unsigned short*)alloc(SZ_MB);
  unsigned short* Ab[10];                      // A^2..A^1024 bf16
  for (int i = 0; i < 10; ++i) Ab[i] = (unsigned short*)alloc(SZ_MB);
  unsigned short* Bmb = (unsigned short*)alloc(SZ_MB);
  unsigned short* Cmb = (unsigned short*)alloc(SZ_MB);
  unsigned short* gwb = (unsigned short*)alloc(SZ_MB);
  unsigned short* zp  = (unsigned short*)alloc(1024 * sizeof(unsigned short));

  if ((size_t)(p - (char*)d_ws) > ws_size) return;  // workspace too small

  k_abuild<<<dim3(768, 4), 256, 0, stream>>>(U, V, S, Bm, Cm, gw,
      Af, AfT, Abf, Bmb, Cmb, gwb, zp);
  k_rms<<<4096, 256, 0, stream>>>(x, scale, xn);

  // squaring chain: A -> A^2 -> ... -> A^1024 (bf16 emitted each step)
  const float* sx = Af; const float* sxt = AfT;
  float* za = P1; float* zat = P1T; float* zb = P2; float* zbt = P2T;
  for (int i = 0; i < 10; ++i) {
    k_sq<<<dim3(12, 6), 512, 0, stream>>>(sx, sxt, za, zat, Ab[i]);
    sx = za; sxt = zat;
    float* t1 = za; float* t2 = zat; za = zb; zat = zbt; zb = t1; zbt = t2;
  }

  // u = xn@Bm^T, duplicated into fwd+bwd halves of XA
  k_gemm<0><<<768, 256, 0, stream>>>(xn, Bmb, nullptr, XA, zp, 0, 1,
      nullptr, nullptr, nullptr, nullptr, nullptr);

  // doubling levels k=1..512 (shift sh=8k rows)
  unsigned short* src = XA; unsigned short* dst = XB;
  for (int i = 0; i < 10; ++i) {
    const unsigned short* W = (i == 0) ? Abf : Ab[i-1];
    k_gemm<0><<<1536, 256, 0, stream>>>(src, W, src, dst, zp, 8 << i, 0,
        nullptr, nullptr, nullptr, nullptr, nullptr);
    unsigned short* t = src; src = dst; dst = t;
  }
  // src = XA holds X_1024 (both dirs). Last level (k=1024) + fwd/bwd sum:
  k_gemm<1><<<768, 256, 0, stream>>>(src, Ab[9], src, XB, zp, 8192, 0,
      nullptr, nullptr, nullptr, nullptr, nullptr);

  // y = Xsum@Cm^T
  unsigned short* ybuf = XB + (size_t)16384 * Hn;
  k_gemm<0><<<768, 256, 0, stream>>>(XB, Cmb, nullptr, ybuf, zp, 0, 0,
      nullptr, nullptr, nullptr, nullptr, nullptr);

  // out = x + alpha*0.5*y*sigmoid(xn@gw^T+gb)
  k_gemm<2><<<768, 256, 0, stream>>>(xn, gwb, nullptr, nullptr, zp, 0, 0,
      ybuf, gb, alpha, x, out);
}

// Round 6
// 1283.802 us; speedup vs baseline: 2.7636x; 1.2447x over previous
//
#include <hip/hip_runtime.h>

// ---------------------------------------------------------------------------
// BiSSM global block, MI355X — round 6: log-doubling, min-2-phase dbuf GEMM.
//   u[t]    = xn[t]@Bm^T (dup to fwd+bwd halves)            k_gemm<0>
//   X_2k[t] = X_k[t] + X_k[t-/+k]@(A^k)^T, k=1..512          k_gemm<0> x10
//   Xsum[t] = X_f[t]+X_f[t-1024]@W + X_b[t]+X_b[t+1024]@W    k_gemm<1> (W=A^1024)
//   y       = Xsum@Cm^T                                      k_gemm<0>
//   out     = x + alpha*0.5*y*sigmoid(xn@gw^T+gb)            k_gemm<2>
// GEMM core: 128x128 tile, BK=32, DOUBLE-buffered LDS (2x16KB), stage(t+1)
// issued BEFORE compute(t), ONE __syncthreads per K-step (T3 minimum-2-phase).
// global_load_lds(16B) with chunk swizzle c^( (r^(r>>2))&3 ) -> <=2-way free.
// Epilogue: acc -> LDS bounce -> vectorized res-add + b64/b128 global I/O.
// Powers A^2..A^1024: hi/lo-bf16 f32 squaring chain (k_sq x10).
// ---------------------------------------------------------------------------

typedef short  bfrag __attribute__((ext_vector_type(8)));   // 8 x bf16
typedef float  ffrag __attribute__((ext_vector_type(4)));   // mfma acc
typedef float  f4    __attribute__((ext_vector_type(4)));
typedef short  s4v   __attribute__((ext_vector_type(4)));   // 4 x bf16

#define DEV static __device__ __forceinline__
#define Hn 768

DEV unsigned short f2bf(float f) {
  unsigned u = __float_as_uint(f);
  u += 0x7fffu + ((u >> 16) & 1u);            // round-to-nearest-even
  return (unsigned short)(u >> 16);
}
DEV float bf2f(unsigned short s) { return __uint_as_float(((unsigned)s) << 16); }

DEV ffrag mfma16(bfrag a, bfrag b, ffrag c) {
  return __builtin_amdgcn_mfma_f32_16x16x32_bf16(a, b, c, 0, 0, 0);
}

DEV void glds16(const unsigned short* g, unsigned short* l) {
  __builtin_amdgcn_global_load_lds(
      (const __attribute__((address_space(1))) unsigned int*)g,
      (__attribute__((address_space(3))) unsigned int*)l, 16, 0, 0);
}

union BF8 { bfrag v; unsigned short u[8]; };

// ---------------------------------------------------------------------------
// k_abuild: gridDim = (768, 4); task = blockIdx.y
__global__ __launch_bounds__(256) void k_abuild(
    const float* __restrict__ U, const float* __restrict__ V,
    const float* __restrict__ S, const float* __restrict__ Bm,
    const float* __restrict__ Cm, const float* __restrict__ gw,
    float* __restrict__ Af, float* __restrict__ AfT,
    unsigned short* __restrict__ Abf,
    unsigned short* __restrict__ Bmb, unsigned short* __restrict__ Cmb,
    unsigned short* __restrict__ gwb, unsigned short* __restrict__ zp) {
  int i = blockIdx.x;
  int task = blockIdx.y;
  if (task == 0) {
    float u0 = U[i*4+0], u1 = U[i*4+1], u2 = U[i*4+2], u3 = U[i*4+3];
    for (int j = threadIdx.x; j < Hn; j += 256) {
      float a = u0*V[j*4+0] + u1*V[j*4+1] + u2*V[j*4+2] + u3*V[j*4+3]
              + S[i*Hn+j] - S[j*Hn+i];
      if (i == j) a += -(float)(i+1) / 768.0f;
      Af[i*Hn+j]  = a;
      AfT[j*Hn+i] = a;
      Abf[i*Hn+j] = f2bf(a);
    }
    if (i == 0) for (int j = threadIdx.x; j < 1024; j += 256) zp[j] = 0;
  } else {
    const float* src = (task==1) ? Bm : (task==2) ? Cm : gw;
    unsigned short* dst = (task==1) ? Bmb : (task==2) ? Cmb : gwb;
    for (int j = threadIdx.x; j < Hn; j += 256) dst[i*Hn+j] = f2bf(src[i*Hn+j]);
  }
}

// ---------------------------------------------------------------------------
// k_rms: one wave per row (row = b*2048 + t); write xn in (t,b) order, bf16.
__global__ __launch_bounds__(256) void k_rms(
    const float* __restrict__ x, const float* __restrict__ scale,
    unsigned short* __restrict__ xn) {
  int row  = blockIdx.x * 4 + (threadIdx.x >> 6);
  int lane = threadIdx.x & 63;
  int b = row >> 11, t = row & 2047;
  const float* xr = x + (long)row * Hn;
  float v[12];
  float ss = 0.f;
#pragma unroll
  for (int j = 0; j < 12; ++j) { v[j] = xr[lane + j*64]; ss += v[j]*v[j]; }
#pragma unroll
  for (int off = 1; off < 64; off <<= 1) ss += __shfl_xor(ss, off);
  float inv = 1.0f / sqrtf(ss / 768.0f + 1e-8f);
  unsigned short* dst = xn + ((long)t * 8 + b) * Hn;
#pragma unroll
  for (int j = 0; j < 12; ++j) dst[lane + j*64] = f2bf(v[j] * inv * scale[lane + j*64]);
}

// ---------------------------------------------------------------------------
// k_sq: Z = X @ X, hi/lo bf16 (3 passes). Writes Z rm + Z^T rm f32 + bf16.
// grid (12, 6), 512 thr, tile 64x128.
__global__ __launch_bounds__(512) void k_sq(
    const float* __restrict__ X, const float* __restrict__ XT,
    float* __restrict__ Z, float* __restrict__ ZT,
    unsigned short* __restrict__ Zbf) {
  int tid = threadIdx.x, lane = tid & 63, w = tid >> 6;
  int mw = w >> 2, nw = w & 3, l15 = lane & 15, lhi = lane >> 4;
  int rb = blockIdx.x * 64, cb = blockIdx.y * 128;
  ffrag acc[2][2] = {};
  for (int kt = 0; kt < 24; ++kt) {
    int k0 = kt*32 + lhi*8;
    BF8 ah[2], al[2], bh[2], bl[2];
#pragma unroll
    for (int mt = 0; mt < 2; ++mt) {
      const f4* p = (const f4*)(X + (long)(rb + mw*32 + mt*16 + l15) * Hn + k0);
      f4 x0 = p[0], x1 = p[1];
#pragma unroll
      for (int j = 0; j < 8; ++j) {
        float f = (j < 4) ? x0[j] : x1[j-4];
        unsigned short h = f2bf(f);
        ah[mt].u[j] = h; al[mt].u[j] = f2bf(f - bf2f(h));
      }
    }
#pragma unroll
    for (int nt = 0; nt < 2; ++nt) {
      const f4* p = (const f4*)(XT + (long)(cb + nw*32 + nt*16 + l15) * Hn + k0);
      f4 x0 = p[0], x1 = p[1];
#pragma unroll
      for (int j = 0; j < 8; ++j) {
        float f = (j < 4) ? x0[j] : x1[j-4];
        unsigned short h = f2bf(f);
        bh[nt].u[j] = h; bl[nt].u[j] = f2bf(f - bf2f(h));
      }
    }
#pragma unroll
    for (int mt = 0; mt < 2; ++mt)
#pragma unroll
      for (int nt = 0; nt < 2; ++nt) {
        acc[mt][nt] = mfma16(ah[mt].v, bh[nt].v, acc[mt][nt]);
        acc[mt][nt] = mfma16(ah[mt].v, bl[nt].v, acc[mt][nt]);
        acc[mt][nt] = mfma16(al[mt].v, bh[nt].v, acc[mt][nt]);
      }
  }
#pragma unroll
  for (int mt = 0; mt < 2; ++mt)
#pragma unroll
    for (int nt = 0; nt < 2; ++nt)
#pragma unroll
      for (int q = 0; q < 4; ++q) {
        int grow = rb + mw*32 + mt*16 + lhi*4 + q;
        int gcol = cb + nw*32 + nt*16 + l15;
        float vv = acc[mt][nt][q];
        Z[(long)grow*Hn + gcol] = vv;
        ZT[(long)gcol*Hn + grow] = vv;
        Zbf[(long)grow*Hn + gcol] = f2bf(vv);
      }
}

// ---------------------------------------------------------------------------
// k_gemm<MODE>: 128x128 tile, BK=32, 24 K-steps, 256 thr (4 waves, 2x2 of
// 64x64). Min-2-phase: double-buffered LDS, stage(t+1) before compute(t),
// one barrier per step. Chunk swizzle: c ^ ((r ^ (r>>2)) & 3).
// MODE 0: outb = [res +] A0[row -/+ sh] @ B0^T ; dup -> also write +16384.
// MODE 1: outb[r] = res[r]+res[r+16384] + (A0[r-sh] + A0[r+16384+sh]) @ B0^T
// MODE 2: outf = x + alpha*0.5*yb*sigmoid(A0@B0^T + gb)   (row = t*8+b)
template<int MODE>
__global__ __launch_bounds__(256) void k_gemm(
    const unsigned short* __restrict__ A0s, const unsigned short* __restrict__ B0s,
    const unsigned short* __restrict__ res, unsigned short* __restrict__ outb,
    const unsigned short* __restrict__ zp, int sh, int dup,
    const unsigned short* __restrict__ yb,
    const float* __restrict__ gb, const float* __restrict__ alpha,
    const float* __restrict__ x, float* __restrict__ outf) {
  constexpr int NA = (MODE == 1) ? 2 : 1;     // A streams
  constexpr int NT = NA + 1;                   // tiles per buffer (A.. + B)
  __shared__ unsigned short lds[2][NT * 4096]; // 2 x NT x 8KB

  const int tid = threadIdx.x, lane = tid & 63, w = tid >> 6;
  const int l15 = lane & 15, lhi = lane >> 4;
  const int wr = w >> 1, wc = w & 1;

  // XCD-aware bijective block swizzle (m204), col-fast decompose (ncol=6).
  const int nwg = gridDim.x;
  const int q8 = nwg >> 3, r8 = nwg & 7, xcd = blockIdx.x & 7, fo = blockIdx.x >> 3;
  const int wg = (xcd < r8 ? xcd*(q8+1) : r8*(q8+1) + (xcd - r8)*q8) + fo;
  const int cb = wg % 6, rbk = wg / 6;
  const long r0 = (long)rbk * 128;
  const long bc0 = (long)cb * 128;
  const int dir = (MODE == 0 && r0 >= 16384) ? 1 : 0;

  bool skip = false;
  if (MODE == 0 && sh > 0)
    skip = dir ? (r0 >= 32768 - sh) : (r0 + 128 <= sh);

  // staging geometry: inst = w*2+jj covers rows inst*16..+15 (1KB each);
  // lane: rowin = lane>>2, chunk ch = lane&3; source chunk c = ch ^ XS(r).
  const int rowin = lane >> 2, ch = lane & 3;
  long gA[NA][2]; bool vA[NA][2]; long gB[2]; int lbase[2];
#pragma unroll
  for (int jj = 0; jj < 2; ++jj) {
    const int inst = w*2 + jj;
    const int r = inst*16 + rowin;
    const int c = ch ^ ((r ^ (r >> 2)) & 3);
    lbase[jj] = inst * 512;
#pragma unroll
    for (int s = 0; s < NA; ++s) {
      long gr; bool ok = true;
      if (MODE == 0) {
        gr = r0 + r + (dir ? sh : -sh);
        ok = dir ? (gr < 32768) : (gr >= 0);
      } else if (MODE == 1) {
        if (s == 0) { gr = r0 + r - sh; ok = (gr >= 0); }
        else        { gr = r0 + r + 16384 + sh; ok = (gr < 32768); }
      } else {
        gr = r0 + r;
      }
      vA[s][jj] = ok; gA[s][jj] = gr * Hn + c*8;
    }
    gB[jj] = (bc0 + r) * Hn + c*8;
  }

  auto stage = [&](int buf, int kt) {
    const int ko = kt * 32;
#pragma unroll
    for (int jj = 0; jj < 2; ++jj) {
#pragma unroll
      for (int s = 0; s < NA; ++s) {
        const unsigned short* g = vA[s][jj] ? (A0s + gA[s][jj] + ko) : zp;
        glds16(g, &lds[buf][s*4096 + lbase[jj]]);
      }
      glds16(B0s + gB[jj] + ko, &lds[buf][NA*4096 + lbase[jj]]);
    }
  };

  ffrag acc[4][4] = {};
  const int cx = (lhi ^ ((l15 ^ (l15 >> 2)) & 3)) * 8;   // swizzled read chunk

  if (!skip) {
    stage(0, 0);
    __syncthreads();                       // drain vmcnt: buf0 ready
    int cur = 0;
    for (int kt = 0; kt < 24; ++kt) {
      if (kt < 23) stage(cur ^ 1, kt + 1); // issue next tile BEFORE compute
      bfrag a[NA][4], b[4];
#pragma unroll
      for (int mt = 0; mt < 4; ++mt) {
        const int row = wr*64 + mt*16 + l15;
#pragma unroll
        for (int s = 0; s < NA; ++s)
          a[s][mt] = *(const bfrag*)&lds[cur][s*4096 + row*32 + cx];
      }
#pragma unroll
      for (int nt = 0; nt < 4; ++nt) {
        const int row = wc*64 + nt*16 + l15;
        b[nt] = *(const bfrag*)&lds[cur][NA*4096 + row*32 + cx];
      }
#pragma unroll
      for (int mt = 0; mt < 4; ++mt)
#pragma unroll
        for (int nt = 0; nt < 4; ++nt) {
          acc[mt][nt] = mfma16(a[0][mt], b[nt], acc[mt][nt]);
          if (NA == 2) acc[mt][nt] = mfma16(a[1][mt], b[nt], acc[mt][nt]);
        }
      __syncthreads();                     // drains stage; next buf ready
      cur ^= 1;
    }
  }

  // ------ epilogue: acc -> LDS bounce (f32) -> vectorized global I/O ------
  float* fl = (float*)&lds[0][0];          // 32KB = 64 rows x 128 cols f32
  const float al = (MODE == 2) ? alpha[0] : 0.f;
#pragma unroll
  for (int hh = 0; hh < 2; ++hh) {
    __syncthreads();
    if (wr == hh) {
#pragma unroll
      for (int mt = 0; mt < 4; ++mt)
#pragma unroll
        for (int nt = 0; nt < 4; ++nt)
#pragma unroll
          for (int q = 0; q < 4; ++q)
            fl[(mt*16 + lhi*4 + q)*128 + wc*64 + nt*16 + l15] = acc[mt][nt][q];
    }
    __syncthreads();
    for (int i = tid; i < 2048; i += 256) {
      const int row = i >> 5;
      const int cc  = (i & 31) << 2;
      f4 v = *(const f4*)&fl[row*128 + cc];
      const long grow = r0 + hh*64 + row;
      const long gcol = bc0 + cc;
      const long go = grow * Hn + gcol;
      if (MODE == 0) {
        if (res) {
          s4v rv = *(const s4v*)&res[go];
#pragma unroll
          for (int j = 0; j < 4; ++j) v[j] += bf2f(((unsigned short*)&rv)[j]);
        }
        s4v ov;
#pragma unroll
        for (int j = 0; j < 4; ++j) ((unsigned short*)&ov)[j] = f2bf(v[j]);
        *(s4v*)&outb[go] = ov;
        if (dup) *(s4v*)&outb[go + (long)16384*Hn] = ov;
      } else if (MODE == 1) {
        s4v ra = *(const s4v*)&res[go];
        s4v rb2 = *(const s4v*)&res[go + (long)16384*Hn];
#pragma unroll
        for (int j = 0; j < 4; ++j)
          v[j] += bf2f(((unsigned short*)&ra)[j]) + bf2f(((unsigned short*)&rb2)[j]);
        s4v ov;
#pragma unroll
        for (int j = 0; j < 4; ++j) ((unsigned short*)&ov)[j] = f2bf(v[j]);
        *(s4v*)&outb[go] = ov;
      } else {
        f4 gbv = *(const f4*)&gb[gcol];
        s4v yv = *(const s4v*)&yb[go];
        const long t = grow >> 3, b = grow & 7;
        const long o = (b*2048 + t)*Hn + gcol;
        f4 xv = *(const f4*)&x[o];
        f4 ov;
#pragma unroll
        for (int j = 0; j < 4; ++j) {
          float z = v[j] + gbv[j];
          float g = 1.0f / (1.0f + __expf(-z));
          ov[j] = xv[j] + al * 0.5f * bf2f(((unsigned short*)&yv)[j]) * g;
        }
        *(f4*)&outf[o] = ov;
      }
    }
  }
}

// ---------------------------------------------------------------------------
extern "C" void kernel_launch(void* const* d_in, const int* in_sizes, int n_in,
                              void* d_out, int out_size, void* d_ws, size_t ws_size,
                              hipStream_t stream) {
  const float* x     = (const float*)d_in[0];
  const float* scale = (const float*)d_in[1];
  const float* U     = (const float*)d_in[2];
  const float* V     = (const float*)d_in[3];
  const float* S     = (const float*)d_in[4];
  const float* Bm    = (const float*)d_in[5];
  const float* Cm    = (const float*)d_in[6];
  const float* gw    = (const float*)d_in[7];
  const float* gb    = (const float*)d_in[8];
  const float* alpha = (const float*)d_in[9];
  float* out = (float*)d_out;

  char* p = (char*)d_ws;
  auto alloc = [&](size_t sz) { char* r = p; p += (sz + 255) & ~(size_t)255; return r; };

  const size_t SZ_X  = (size_t)32768 * Hn * sizeof(unsigned short);  // 50.3MB
  const size_t SZ_BF = (size_t)16384 * Hn * sizeof(unsigned short);  // 25.2MB
  const size_t SZ_M  = (size_t)Hn * Hn * sizeof(float);              // 2.36MB
  const size_t SZ_MB = (size_t)Hn * Hn * sizeof(unsigned short);     // 1.18MB

  unsigned short* xn = (unsigned short*)alloc(SZ_BF);
  unsigned short* XA = (unsigned short*)alloc(SZ_X);
  unsigned short* XB = (unsigned short*)alloc(SZ_X);
  float* Af  = (float*)alloc(SZ_M);
  float* AfT = (float*)alloc(SZ_M);
  float* P1  = (float*)alloc(SZ_M);
  float* P1T = (float*)alloc(SZ_M);
  float* P2  = (float*)alloc(SZ_M);
  float* P2T = (float*)alloc(SZ_M);
  unsigned short* Abf = (unsigned short*)alloc(SZ_MB);
  unsigned short* Ab[10];                      // A^2..A^1024 bf16
  for (int i = 0; i < 10; ++i) Ab[i] = (unsigned short*)alloc(SZ_MB);
  unsigned short* Bmb = (unsigned short*)alloc(SZ_MB);
  unsigned short* Cmb = (unsigned short*)alloc(SZ_MB);
  unsigned short* gwb = (unsigned short*)alloc(SZ_MB);
  unsigned short* zp  = (unsigned short*)alloc(1024 * sizeof(unsigned short));

  if ((size_t)(p - (char*)d_ws) > ws_size) return;  // workspace too small

  k_abuild<<<dim3(768, 4), 256, 0, stream>>>(U, V, S, Bm, Cm, gw,
      Af, AfT, Abf, Bmb, Cmb, gwb, zp);
  k_rms<<<4096, 256, 0, stream>>>(x, scale, xn);

  // squaring chain: A -> A^2 -> ... -> A^1024 (bf16 emitted each step)
  const float* sx = Af; const float* sxt = AfT;
  float* za = P1; float* zat = P1T; float* zb = P2; float* zbt = P2T;
  for (int i = 0; i < 10; ++i) {
    k_sq<<<dim3(12, 6), 512, 0, stream>>>(sx, sxt, za, zat, Ab[i]);
    sx = za; sxt = zat;
    float* t1 = za; float* t2 = zat; za = zb; zat = zbt; zb = t1; zbt = t2;
  }

  // u = xn@Bm^T, duplicated into fwd+bwd halves of XA
  k_gemm<0><<<768, 256, 0, stream>>>(xn, Bmb, nullptr, XA, zp, 0, 1,
      nullptr, nullptr, nullptr, nullptr, nullptr);

  // doubling levels k=1..512 (shift sh=8k rows)
  unsigned short* src = XA; unsigned short* dst = XB;
  for (int i = 0; i < 10; ++i) {
    const unsigned short* W = (i == 0) ? Abf : Ab[i-1];
    k_gemm<0><<<1536, 256, 0, stream>>>(src, W, src, dst, zp, 8 << i, 0,
        nullptr, nullptr, nullptr, nullptr, nullptr);
    unsigned short* t = src; src = dst; dst = t;
  }
  // src holds X_1024 (both dirs). Last level (k=1024) + fwd/bwd sum:
  k_gemm<1><<<768, 256, 0, stream>>>(src, Ab[9], src, XB, zp, 8192, 0,
      nullptr, nullptr, nullptr, nullptr, nullptr);

  // y = Xsum@Cm^T
  unsigned short* ybuf = XB + (size_t)16384 * Hn;
  k_gemm<0><<<768, 256, 0, stream>>>(XB, Cmb, nullptr, ybuf, zp, 0, 0,
      nullptr, nullptr, nullptr, nullptr, nullptr);

  // out = x + alpha*0.5*y*sigmoid(xn@gw^T+gb)
  k_gemm<2><<<768, 256, 0, stream>>>(xn, gwb, nullptr, nullptr, zp, 0, 0,
      ybuf, gb, alpha, x, out);
}